// Round 8
// baseline (973.404 us; speedup 1.0000x reference)
//
#include <hip/hip_runtime.h>
#include <hip/hip_cooperative_groups.h>
#include <cstdint>
#include <cstddef>

namespace cg = cooperative_groups;

// GCN on MI355X, round 8.
//   out[50000,64] = log_softmax(gcn2(relu(gcn1(x))))
// - ALL preprocessing fused into one cooperative kernel (grid.sync phases):
//   zero -> hist(+rank) -> bsum -> bscan -> scan(+pad) -> wstart+fill
// - agg128: XCD-pinned column slices via s_getreg(HW_REG_XCC_ID); per-slice
//   atomic chunk counters + stealing => correct under ANY dispatch mapping,
//   L2-resident (3.2MB slice < 4MiB XCD L2) in the common case.
// - agg64ls: round-6 form (full wave per edge-quad via uint4 desc loads).

#define N_FEAT 128
#define NWAVE_B 8192   // agg64 waves
#define NCHUNK_A 2048  // agg128 row chunks
#define NB_BUILD 512   // cooperative build grid

typedef short bf16x8 __attribute__((ext_vector_type(8)));
typedef float f32x4 __attribute__((ext_vector_type(4)));

__device__ __forceinline__ unsigned f2bf(float f) {
  unsigned u = __float_as_uint(f);
  return (u + 0x7FFFu + ((u >> 16) & 1u)) >> 16;   // round-to-nearest-even
}
__device__ __forceinline__ float bflo(unsigned u) { return __uint_as_float(u << 16); }
__device__ __forceinline__ float bfhi(unsigned u) { return __uint_as_float(u & 0xFFFF0000u); }

__device__ __forceinline__ int rp_lower_bound(const int* __restrict__ rowptr,
                                              int n, int target) {
  int lo = 0, hi = n;
  while (lo < hi) {
    int mid = (lo + hi) >> 1;
    if (rowptr[mid] < target) lo = mid + 1; else hi = mid;
  }
  return lo;
}

// ---------------- fused preprocessing (cooperative) ----------------

__global__ __launch_bounds__(256) void k_build(const int* __restrict__ src,
                                               const int* __restrict__ dst,
                                               int* __restrict__ cnt,
                                               int* __restrict__ rank,
                                               int* __restrict__ bsum,
                                               int* __restrict__ bbase,
                                               int* __restrict__ rowptr,
                                               float* __restrict__ dinv,
                                               unsigned* __restrict__ desc,
                                               int* __restrict__ wsA,
                                               int* __restrict__ wsB,
                                               int* __restrict__ ctr,
                                               int n, int E) {
  cg::grid_group grid = cg::this_grid();
  int t = threadIdx.x, b = blockIdx.x;
  int gtid = b * 256 + t, gstride = gridDim.x * 256;
  int nb = (n + 255) >> 8;
  __shared__ int lds[256];
  __shared__ int wsum[4];

  // A: zero counters
  for (int i = gtid; i < n; i += gstride) cnt[i] = 0;
  if (gtid < 8) ctr[gtid] = 0;
  grid.sync();

  // B: histogram + per-edge rank
  for (int e = gtid; e < E; e += gstride) rank[e] = atomicAdd(&cnt[dst[e]], 1);
  grid.sync();

  // C: per-block sums of padded counts
  if (b < nb) {
    int i = b * 256 + t;
    int v = (i < n) ? ((cnt[i] + 3) & ~3) : 0;
    for (int o = 32; o > 0; o >>= 1) v += __shfl_down(v, o);
    if ((t & 63) == 0) wsum[t >> 6] = v;
    __syncthreads();
    if (t == 0) bsum[b] = wsum[0] + wsum[1] + wsum[2] + wsum[3];
  }
  grid.sync();

  // D: scan of block sums (block 0)
  if (b == 0) {
    int v = (t < nb) ? bsum[t] : 0;
    lds[t] = v;
    __syncthreads();
    for (int o = 1; o < 256; o <<= 1) {
      int u = (t >= o) ? lds[t - o] : 0;
      __syncthreads();
      lds[t] += u;
      __syncthreads();
    }
    if (t < nb) bbase[t] = lds[t] - v;
  }
  grid.sync();

  // E: local scan -> rowptr/dinv, zero pad slots
  if (b < nb) {
    int i = b * 256 + t;
    int c = (i < n) ? cnt[i] : 0;
    int pc = (c + 3) & ~3;
    lds[t] = pc;
    __syncthreads();
    for (int o = 1; o < 256; o <<= 1) {
      int u = (t >= o) ? lds[t - o] : 0;
      __syncthreads();
      lds[t] += u;
      __syncthreads();
    }
    if (i < n) {
      int excl = bbase[b] + lds[t] - pc;
      rowptr[i] = excl;
      dinv[i] = rsqrtf((float)(c + 1));        // +1 self-loop
      for (int p = excl + c; p < excl + pc; ++p) desc[p] = 0;
      if (i == n - 1) rowptr[n] = excl + pc;
    }
  }
  grid.sync();

  // F: wave-partitions + CSR fill
  int Ep = rowptr[n];
  for (int w = gtid; w <= NWAVE_B; w += gstride)
    wsB[w] = (w == NWAVE_B) ? n
           : rp_lower_bound(rowptr, n, (int)((long long)Ep * w / NWAVE_B));
  for (int w = gtid; w <= NCHUNK_A; w += gstride)
    wsA[w] = (w == NCHUNK_A) ? n
           : rp_lower_bound(rowptr, n, (int)((long long)Ep * w / NCHUNK_A));
  for (int e = gtid; e < E; e += gstride) {
    int s = src[e], d = dst[e];
    desc[rowptr[d] + rank[e]] = (f2bf(dinv[s] * dinv[d]) << 16) | (unsigned)s;
  }
}

// ---------------- MFMA GEMMs (round-6, unchanged) ----------------

template<int NCOL, bool XF32>
__global__ __launch_bounds__(256) void k_gemm_mfma(const void* __restrict__ Xv,
                                                   const float* __restrict__ W,
                                                   unsigned short* __restrict__ Yb,
                                                   int n) {
  constexpr int NT = NCOL / 16;
  __shared__ uint4 Xl[64][16];
  __shared__ uint4 Wl[NCOL][16];
  int t = threadIdx.x;
  int row0 = blockIdx.x * 64;

  for (int c = t; c < 1024; c += 256) {
    int lr = c >> 4, kc = c & 15;
    int row = row0 + lr;
    uint4 v = {0u, 0u, 0u, 0u};
    if (row < n) {
      if constexpr (XF32) {
        const float* Xf = (const float*)Xv;
        float4 f0 = *(const float4*)(Xf + (size_t)row * 128 + kc * 8);
        float4 f1 = *(const float4*)(Xf + (size_t)row * 128 + kc * 8 + 4);
        v.x = f2bf(f0.x) | (f2bf(f0.y) << 16);
        v.y = f2bf(f0.z) | (f2bf(f0.w) << 16);
        v.z = f2bf(f1.x) | (f2bf(f1.y) << 16);
        v.w = f2bf(f1.z) | (f2bf(f1.w) << 16);
      } else {
        v = ((const uint4*)Xv)[(size_t)row * 16 + kc];
      }
    }
    Xl[lr][kc ^ (lr & 7)] = v;
  }
  {
    int j = t % NCOL, kc0 = t / NCOL;
    for (int kc = kc0; kc < 16; kc += 256 / NCOL) {
      const float* wp = W + (size_t)(kc * 8) * NCOL + j;
      float f[8];
#pragma unroll
      for (int e = 0; e < 8; ++e) f[e] = wp[e * NCOL];
      uint4 v;
      v.x = f2bf(f[0]) | (f2bf(f[1]) << 16);
      v.y = f2bf(f[2]) | (f2bf(f[3]) << 16);
      v.z = f2bf(f[4]) | (f2bf(f[5]) << 16);
      v.w = f2bf(f[6]) | (f2bf(f[7]) << 16);
      Wl[j][kc ^ (j & 7)] = v;
    }
  }
  __syncthreads();

  int w = t >> 6, lane = t & 63;
  int lr16 = lane & 15, kg = lane >> 4;
  bf16x8 a[4];
#pragma unroll
  for (int kk = 0; kk < 4; ++kk)
    a[kk] = __builtin_bit_cast(bf16x8, Xl[w * 16 + lr16][(kk * 4 + kg) ^ (lane & 7)]);
#pragma unroll
  for (int jt = 0; jt < NT; ++jt) {
    f32x4 acc = {0.0f, 0.0f, 0.0f, 0.0f};
#pragma unroll
    for (int kk = 0; kk < 4; ++kk) {
      bf16x8 bb = __builtin_bit_cast(bf16x8, Wl[jt * 16 + lr16][(kk * 4 + kg) ^ (lane & 7)]);
      acc = __builtin_amdgcn_mfma_f32_16x16x32_bf16(a[kk], bb, acc, 0, 0, 0);
    }
    int col = jt * 16 + lr16;
#pragma unroll
    for (int r = 0; r < 4; ++r) {
      int row = row0 + w * 16 + kg * 4 + r;
      if (row < n) Yb[(size_t)row * NCOL + col] = (unsigned short)f2bf(acc[r]);
    }
  }
}

// ---------------- aggregations ----------------

// Layer-1, XCD-pinned slices: wave's slice = (XCC_ID + o) & 3, chunks taken
// from per-slice atomic counters (steal other slices after own exhausted).
// Quad q=lane>>4 handles edge base+q; c=lane&15 owns uint co=s*16+c (2 cols).
__global__ __launch_bounds__(256) void k_agg128x(const unsigned* __restrict__ desc,
                                                 const int* __restrict__ rowptr,
                                                 const int* __restrict__ wsA,
                                                 const float* __restrict__ dinv,
                                                 const float* __restrict__ bias,
                                                 const unsigned* __restrict__ xwb,
                                                 unsigned* __restrict__ hb,
                                                 int* __restrict__ ctr, int n) {
  int xcc;
  asm volatile("s_getreg_b32 %0, hwreg(HW_REG_XCC_ID)" : "=s"(xcc));
  int lane = threadIdx.x & 63;
  int q = lane >> 4, c = lane & 15;
  for (int o = 0; o < 4; ++o) {
    int s = (xcc + o) & 3;
    int co = s * 16 + c;
    float b0 = bias[2 * co], b1 = bias[2 * co + 1];
    for (;;) {
      int ch = 0;
      if (lane == 0) ch = atomicAdd(&ctr[s], 1);
      ch = __shfl(ch, 0);
      if (ch >= NCHUNK_A) break;
      int r0 = wsA[ch], r1 = wsA[ch + 1];
      if (r0 >= r1) continue;
      int beg = rowptr[r0];
      for (int r = r0; r < r1; ++r) {
        int end = rowptr[r + 1];
        float ax = 0.0f, ay = 0.0f, bx = 0.0f, by = 0.0f;
        if (q == 0) {                        // self-loop + bias counted once
          float di = dinv[r];
          float sl = di * di;
          unsigned us = xwb[(size_t)r * 64 + co];
          ax = b0 + bflo(us) * sl;
          ay = b1 + bfhi(us) * sl;
        }
        int base = beg;
        for (; base + 8 <= end; base += 8) { // 8 edges/iter (2 per quad)
          unsigned d0 = desc[base + q];
          unsigned d1 = desc[base + 4 + q];
          unsigned u0 = xwb[(size_t)(d0 & 0xFFFFu) * 64 + co];
          unsigned u1 = xwb[(size_t)(d1 & 0xFFFFu) * 64 + co];
          float n0 = bfhi(d0), n1 = bfhi(d1);
          ax += bflo(u0) * n0; ay += bfhi(u0) * n0;
          bx += bflo(u1) * n1; by += bfhi(u1) * n1;
        }
        if (base < end) {
          unsigned d0 = desc[base + q];
          unsigned u0 = xwb[(size_t)(d0 & 0xFFFFu) * 64 + co];
          float n0 = bfhi(d0);
          ax += bflo(u0) * n0; ay += bfhi(u0) * n0;
        }
        ax += bx; ay += by;
        ax += __shfl_xor(ax, 16); ax += __shfl_xor(ax, 32);
        ay += __shfl_xor(ay, 16); ay += __shfl_xor(ay, 32);
        if (q == 0) {
          float ox = fmaxf(ax, 0.0f), oy = fmaxf(ay, 0.0f);
          hb[(size_t)r * 64 + co] = f2bf(ox) | (f2bf(oy) << 16);
        }
        beg = end;
      }
    }
  }
}

// Layer-2 + log_softmax (round-6 form): half-wave per edge-pair.
__global__ __launch_bounds__(256) void k_agg64ls(const unsigned* __restrict__ desc,
                                                 const int* __restrict__ rowptr,
                                                 const int* __restrict__ wsB,
                                                 const float* __restrict__ dinv,
                                                 const float* __restrict__ bias,
                                                 const unsigned* __restrict__ hwb,
                                                 float* __restrict__ out, int n) {
  int w    = (blockIdx.x * blockDim.x + threadIdx.x) >> 6;
  int lane = threadIdx.x & 63;
  if (w >= NWAVE_B) return;
  int r0 = wsB[w], r1 = wsB[w + 1];
  if (r0 >= r1) return;
  int c    = lane & 31;
  int half = lane >> 5;
  float bc0 = bias[2 * c], bc1 = bias[2 * c + 1];
  int beg = rowptr[r0];
  for (int r = r0; r < r1; ++r) {
    int end = rowptr[r + 1];
    float ax = 0.0f, ay = 0.0f, bx = 0.0f, by = 0.0f;
    if (half == 0) {   // self-loop + bias counted once
      float di = dinv[r];
      unsigned us = hwb[(size_t)r * 32 + c];
      ax = bc0 + bflo(us) * di * di;
      ay = bc1 + bfhi(us) * di * di;
    }
    for (int base = beg; base < end; base += 4) {
      uint4 d4 = *(const uint4*)(desc + base);
      unsigned dA = half ? d4.z : d4.x;
      unsigned dB = half ? d4.w : d4.y;
      unsigned uA = hwb[(size_t)(dA & 0xFFFFu) * 32 + c];
      unsigned uB = hwb[(size_t)(dB & 0xFFFFu) * 32 + c];
      float nA = bfhi(dA), nB = bfhi(dB);
      ax += bflo(uA) * nA; ay += bfhi(uA) * nA;
      bx += bflo(uB) * nB; by += bfhi(uB) * nB;
    }
    float vx = ax + bx, vy = ay + by;
    vx += __shfl_xor(vx, 32);
    vy += __shfl_xor(vy, 32);
    float m = fmaxf(vx, vy);
    for (int o = 16; o > 0; o >>= 1) m = fmaxf(m, __shfl_xor(m, o));
    float s = expf(vx - m) + expf(vy - m);
    for (int o = 16; o > 0; o >>= 1) s += __shfl_xor(s, o);
    float ls = logf(s);
    if (half == 0) {
      float2 o2 = { vx - m - ls, vy - m - ls };
      *(float2*)(out + (size_t)r * 64 + 2 * c) = o2;
    }
    beg = end;
  }
}

extern "C" void kernel_launch(void* const* d_in, const int* in_sizes, int n_in,
                              void* d_out, int out_size, void* d_ws, size_t ws_size,
                              hipStream_t stream) {
  const float* x  = (const float*)d_in[0];
  const int*   ei = (const int*)d_in[1];
  const float* W1 = (const float*)d_in[2];
  const float* b1 = (const float*)d_in[3];
  const float* W2 = (const float*)d_in[4];
  const float* b2 = (const float*)d_in[5];
  float* out = (float*)d_out;

  int n = in_sizes[0] / N_FEAT;   // 50000
  int E = in_sizes[1] / 2;        // 800000
  const int* src = ei;
  const int* dst = ei + E;

  auto align = [](size_t v) { return (v + 255) & ~(size_t)255; };
  char* ws = (char*)d_ws;
  size_t off = 0;
  int*      cnt    = (int*)     (ws + off); off += align((size_t)n * 4);
  int*      rowptr = (int*)     (ws + off); off += align((size_t)(n + 1) * 4);
  float*    dinv   = (float*)   (ws + off); off += align((size_t)n * 4);
  int*      rank   = (int*)     (ws + off); off += align((size_t)E * 4);
  int*      bsum   = (int*)     (ws + off); off += align(256 * 4);
  int*      bbase  = (int*)     (ws + off); off += align(256 * 4);
  int*      wsA    = (int*)     (ws + off); off += align((size_t)(NCHUNK_A + 1) * 4);
  int*      wsB    = (int*)     (ws + off); off += align((size_t)(NWAVE_B + 1) * 4);
  int*      ctr    = (int*)     (ws + off); off += align(8 * 4);
  unsigned* desc   = (unsigned*)(ws + off); off += align((size_t)(E + 4 * n) * 4);
  unsigned* xwb    = (unsigned*)(ws + off); off += align((size_t)n * 64 * 4);  // bf16[n,128]
  unsigned* hb     = (unsigned*)(ws + off); off += align((size_t)n * 64 * 4);  // bf16[n,128]
  unsigned* hwb    = xwb;  // bf16[n,64] overlays xwb (dead after agg128)

  // Fused preprocessing (cooperative: 6 grid-sync'd phases)
  {
    void* args[] = { (void*)&src, (void*)&dst, (void*)&cnt, (void*)&rank,
                     (void*)&bsum, (void*)&bbase, (void*)&rowptr, (void*)&dinv,
                     (void*)&desc, (void*)&wsA, (void*)&wsB, (void*)&ctr,
                     (void*)&n, (void*)&E };
    hipLaunchCooperativeKernel((const void*)k_build, dim3(NB_BUILD), dim3(256),
                               args, 0, stream);
  }

  // Layer 1
  k_gemm_mfma<128, true><<<(n + 63) / 64, 256, 0, stream>>>(
      x, W1, (unsigned short*)xwb, n);
  k_agg128x<<<2048, 256, 0, stream>>>(desc, rowptr, wsA, dinv, b1, xwb, hb, ctr, n);

  // Layer 2
  k_gemm_mfma<64, false><<<(n + 63) / 64, 256, 0, stream>>>(
      hb, W2, (unsigned short*)hwb, n);
  k_agg64ls<<<NWAVE_B / 4, 256, 0, stream>>>(desc, rowptr, wsB, dinv, b2, hwb, out, n);
}

// Round 9
// 319.982 us; speedup vs baseline: 3.0421x; 3.0421x over previous
//
#include <hip/hip_runtime.h>
#include <cstdint>
#include <cstddef>

// GCN on MI355X, round 9: source-striped bucketed CSR + LDS-acc aggregation.
//   out[50000,64] = log_softmax(gcn2(relu(gcn1(x))))
// Edges bucketed by source stripe b(s)=(s>>11)&3 (4 x ~3.2MB table slices).
// Agg kernels loop bucket-outer / rows-inner with per-wave LDS accumulators,
// so the grid's gathers concentrate in one L2-sized slice at a time (soft
// temporal locality, no sync, no placement assumptions).

#define N_FEAT 128
#define RPW 13        // rows per wave in agg kernels

typedef short bf16x8 __attribute__((ext_vector_type(8)));
typedef float f32x4 __attribute__((ext_vector_type(4)));

__device__ __forceinline__ unsigned f2bf(float f) {
  unsigned u = __float_as_uint(f);
  return (u + 0x7FFFu + ((u >> 16) & 1u)) >> 16;   // round-to-nearest-even
}
__device__ __forceinline__ float bflo(unsigned u) { return __uint_as_float(u << 16); }
__device__ __forceinline__ float bfhi(unsigned u) { return __uint_as_float(u & 0xFFFF0000u); }
__device__ __forceinline__ int bkt(int s) { return (s >> 11) & 3; }

// ---------------- preprocessing ----------------

// Histogram over keys (dst*4 + bucket(src)) + per-edge within-key rank.
__global__ void k_hist(const int* __restrict__ src, const int* __restrict__ dst,
                       int* __restrict__ cnt2, int* __restrict__ rank, int E) {
  int e = blockIdx.x * blockDim.x + threadIdx.x;
  if (e >= E) return;
  int key = dst[e] * 4 + bkt(src[e]);
  rank[e] = atomicAdd(&cnt2[key], 1);
}

// Per-block sums of padded key counts; also dinv per row (64 rows/block).
__global__ __launch_bounds__(256) void k_bsum(const int* __restrict__ cnt2,
                                              int* __restrict__ bsum,
                                              float* __restrict__ dinv,
                                              int m, int n) {
  int i = blockIdx.x * 256 + threadIdx.x;
  int v = (i < m) ? ((cnt2[i] + 3) & ~3) : 0;
  for (int o = 32; o > 0; o >>= 1) v += __shfl_down(v, o);
  __shared__ int w[4];
  if ((threadIdx.x & 63) == 0) w[threadIdx.x >> 6] = v;
  __syncthreads();
  if (threadIdx.x == 0) bsum[blockIdx.x] = w[0] + w[1] + w[2] + w[3];
  int row = blockIdx.x * 64 + threadIdx.x;   // first 64 threads: dinv
  if (threadIdx.x < 64 && row < n) {
    int deg = cnt2[4 * row] + cnt2[4 * row + 1] + cnt2[4 * row + 2] + cnt2[4 * row + 3];
    dinv[row] = rsqrtf((float)(deg + 1));    // +1 self-loop
  }
}

__global__ __launch_bounds__(1024) void k_bscan(const int* __restrict__ bsum,
                                                int* __restrict__ bbase, int nb) {
  __shared__ int lds[1024];
  int t = threadIdx.x;
  int v = (t < nb) ? bsum[t] : 0;
  lds[t] = v;
  __syncthreads();
  for (int o = 1; o < 1024; o <<= 1) {
    int u = (t >= o) ? lds[t - o] : 0;
    __syncthreads();
    lds[t] += u;
    __syncthreads();
  }
  if (t < nb) bbase[t] = lds[t] - v;   // exclusive
}

// Local scan over padded key counts -> rp2; zero dummy pad slots.
__global__ __launch_bounds__(256) void k_scan2(const int* __restrict__ cnt2,
                                               const int* __restrict__ bbase,
                                               int* __restrict__ rp2,
                                               unsigned* __restrict__ desc, int m) {
  __shared__ int lds[256];
  int t = threadIdx.x;
  int i = blockIdx.x * 256 + t;
  int c  = (i < m) ? cnt2[i] : 0;
  int pc = (c + 3) & ~3;
  lds[t] = pc;
  __syncthreads();
  for (int o = 1; o < 256; o <<= 1) {
    int u = (t >= o) ? lds[t - o] : 0;
    __syncthreads();
    lds[t] += u;
    __syncthreads();
  }
  if (i < m) {
    int excl = bbase[blockIdx.x] + lds[t] - pc;
    rp2[i] = excl;
    for (int p = excl + c; p < excl + pc; ++p) desc[p] = 0;  // dummy edges
    if (i == m - 1) rp2[m] = excl + pc;
  }
}

__global__ void k_fill(const int* __restrict__ src, const int* __restrict__ dst,
                       const int* __restrict__ rank, const int* __restrict__ rp2,
                       const float* __restrict__ dinv,
                       unsigned* __restrict__ desc, int E) {
  int e = blockIdx.x * blockDim.x + threadIdx.x;
  if (e >= E) return;
  int s = src[e], d = dst[e];
  int p = rp2[d * 4 + bkt(s)] + rank[e];
  desc[p] = (f2bf(dinv[s] * dinv[d]) << 16) | (unsigned)s;
}

// ---------------- MFMA GEMMs (round-6, unchanged) ----------------

template<int NCOL, bool XF32>
__global__ __launch_bounds__(256) void k_gemm_mfma(const void* __restrict__ Xv,
                                                   const float* __restrict__ W,
                                                   unsigned short* __restrict__ Yb,
                                                   int n) {
  constexpr int NT = NCOL / 16;
  __shared__ uint4 Xl[64][16];
  __shared__ uint4 Wl[NCOL][16];
  int t = threadIdx.x;
  int row0 = blockIdx.x * 64;

  for (int c = t; c < 1024; c += 256) {
    int lr = c >> 4, kc = c & 15;
    int row = row0 + lr;
    uint4 v = {0u, 0u, 0u, 0u};
    if (row < n) {
      if constexpr (XF32) {
        const float* Xf = (const float*)Xv;
        float4 f0 = *(const float4*)(Xf + (size_t)row * 128 + kc * 8);
        float4 f1 = *(const float4*)(Xf + (size_t)row * 128 + kc * 8 + 4);
        v.x = f2bf(f0.x) | (f2bf(f0.y) << 16);
        v.y = f2bf(f0.z) | (f2bf(f0.w) << 16);
        v.z = f2bf(f1.x) | (f2bf(f1.y) << 16);
        v.w = f2bf(f1.z) | (f2bf(f1.w) << 16);
      } else {
        v = ((const uint4*)Xv)[(size_t)row * 16 + kc];
      }
    }
    Xl[lr][kc ^ (lr & 7)] = v;
  }
  {
    int j = t % NCOL, kc0 = t / NCOL;
    for (int kc = kc0; kc < 16; kc += 256 / NCOL) {
      const float* wp = W + (size_t)(kc * 8) * NCOL + j;
      float f[8];
#pragma unroll
      for (int e = 0; e < 8; ++e) f[e] = wp[e * NCOL];
      uint4 v;
      v.x = f2bf(f[0]) | (f2bf(f[1]) << 16);
      v.y = f2bf(f[2]) | (f2bf(f[3]) << 16);
      v.z = f2bf(f[4]) | (f2bf(f[5]) << 16);
      v.w = f2bf(f[6]) | (f2bf(f[7]) << 16);
      Wl[j][kc ^ (j & 7)] = v;
    }
  }
  __syncthreads();

  int w = t >> 6, lane = t & 63;
  int lr16 = lane & 15, kg = lane >> 4;
  bf16x8 a[4];
#pragma unroll
  for (int kk = 0; kk < 4; ++kk)
    a[kk] = __builtin_bit_cast(bf16x8, Xl[w * 16 + lr16][(kk * 4 + kg) ^ (lane & 7)]);
#pragma unroll
  for (int jt = 0; jt < NT; ++jt) {
    f32x4 acc = {0.0f, 0.0f, 0.0f, 0.0f};
#pragma unroll
    for (int kk = 0; kk < 4; ++kk) {
      bf16x8 bb = __builtin_bit_cast(bf16x8, Wl[jt * 16 + lr16][(kk * 4 + kg) ^ (lane & 7)]);
      acc = __builtin_amdgcn_mfma_f32_16x16x32_bf16(a[kk], bb, acc, 0, 0, 0);
    }
    int col = jt * 16 + lr16;
#pragma unroll
    for (int r = 0; r < 4; ++r) {
      int row = row0 + w * 16 + kg * 4 + r;
      if (row < n) Yb[(size_t)row * NCOL + col] = (unsigned short)f2bf(acc[r]);
    }
  }
}

// ---------------- aggregations (bucket-outer, LDS acc) ----------------

// Layer-1: wave owns rows [wv*RPW, wv*RPW+RPW). Lane owns cols {2l,2l+1}.
// acc lives in LDS (per-wave private) across the bucket loop.
__global__ __launch_bounds__(256) void k_agg128L(const unsigned* __restrict__ desc,
                                                 const int* __restrict__ rp2,
                                                 const float* __restrict__ dinv,
                                                 const float* __restrict__ bias,
                                                 const unsigned* __restrict__ xwb,
                                                 unsigned* __restrict__ hb, int n) {
  __shared__ float2 acc2[4][RPW][64];
  int wq   = threadIdx.x >> 6;
  int lane = threadIdx.x & 63;
  int wv   = blockIdx.x * 4 + wq;
  int gr0  = wv * RPW;
  if (gr0 >= n) return;
  float b0 = bias[2 * lane], b1 = bias[2 * lane + 1];
  // init: bias + self-loop
  for (int r = 0; r < RPW; ++r) {
    int gr = gr0 + r;
    if (gr >= n) break;
    float di = dinv[gr];
    float sl = di * di;
    unsigned us = xwb[(size_t)gr * 64 + lane];
    acc2[wq][r][lane] = make_float2(b0 + bflo(us) * sl, b1 + bfhi(us) * sl);
  }
  // bucket-outer sweep
  for (int b = 0; b < 4; ++b) {
    for (int r = 0; r < RPW; ++r) {
      int gr = gr0 + r;
      if (gr >= n) break;
      int beg = rp2[4 * gr + b], end = rp2[4 * gr + b + 1];
      if (beg >= end) continue;
      float ax = 0.0f, ay = 0.0f, bx = 0.0f, by = 0.0f;
      for (int base = beg; base < end; base += 4) {
        uint4 d4 = *(const uint4*)(desc + base);
        unsigned u0 = xwb[(size_t)(d4.x & 0xFFFFu) * 64 + lane];
        unsigned u1 = xwb[(size_t)(d4.y & 0xFFFFu) * 64 + lane];
        unsigned u2 = xwb[(size_t)(d4.z & 0xFFFFu) * 64 + lane];
        unsigned u3 = xwb[(size_t)(d4.w & 0xFFFFu) * 64 + lane];
        float n0 = bfhi(d4.x), n1 = bfhi(d4.y), n2 = bfhi(d4.z), n3 = bfhi(d4.w);
        ax += bflo(u0) * n0; ay += bfhi(u0) * n0;
        bx += bflo(u1) * n1; by += bfhi(u1) * n1;
        ax += bflo(u2) * n2; ay += bfhi(u2) * n2;
        bx += bflo(u3) * n3; by += bfhi(u3) * n3;
      }
      float2 a = acc2[wq][r][lane];
      a.x += ax + bx; a.y += ay + by;
      acc2[wq][r][lane] = a;
    }
  }
  // epilogue: relu + pack
  for (int r = 0; r < RPW; ++r) {
    int gr = gr0 + r;
    if (gr >= n) break;
    float2 a = acc2[wq][r][lane];
    hb[(size_t)gr * 64 + lane] = f2bf(fmaxf(a.x, 0.0f)) | (f2bf(fmaxf(a.y, 0.0f)) << 16);
  }
}

// Layer-2 + log_softmax: half-wave per edge-pair; lane owns cols {2c,2c+1}.
__global__ __launch_bounds__(256) void k_agg64L(const unsigned* __restrict__ desc,
                                                const int* __restrict__ rp2,
                                                const float* __restrict__ dinv,
                                                const float* __restrict__ bias,
                                                const unsigned* __restrict__ hwb,
                                                float* __restrict__ out, int n) {
  __shared__ float2 acc2[4][RPW][64];
  int wq   = threadIdx.x >> 6;
  int lane = threadIdx.x & 63;
  int wv   = blockIdx.x * 4 + wq;
  int gr0  = wv * RPW;
  if (gr0 >= n) return;
  int c    = lane & 31;
  int half = lane >> 5;
  float bc0 = bias[2 * c], bc1 = bias[2 * c + 1];
  for (int r = 0; r < RPW; ++r) {
    int gr = gr0 + r;
    if (gr >= n) break;
    float ax = 0.0f, ay = 0.0f;
    if (half == 0) {   // self-loop + bias counted once
      float di = dinv[gr];
      unsigned us = hwb[(size_t)gr * 32 + c];
      ax = bc0 + bflo(us) * di * di;
      ay = bc1 + bfhi(us) * di * di;
    }
    acc2[wq][r][lane] = make_float2(ax, ay);
  }
  for (int b = 0; b < 4; ++b) {
    for (int r = 0; r < RPW; ++r) {
      int gr = gr0 + r;
      if (gr >= n) break;
      int beg = rp2[4 * gr + b], end = rp2[4 * gr + b + 1];
      if (beg >= end) continue;
      float ax = 0.0f, ay = 0.0f, bx = 0.0f, by = 0.0f;
      for (int base = beg; base < end; base += 4) {
        uint4 d4 = *(const uint4*)(desc + base);
        unsigned dA = half ? d4.z : d4.x;
        unsigned dB = half ? d4.w : d4.y;
        unsigned uA = hwb[(size_t)(dA & 0xFFFFu) * 32 + c];
        unsigned uB = hwb[(size_t)(dB & 0xFFFFu) * 32 + c];
        float nA = bfhi(dA), nB = bfhi(dB);
        ax += bflo(uA) * nA; ay += bfhi(uA) * nA;
        bx += bflo(uB) * nB; by += bfhi(uB) * nB;
      }
      float2 a = acc2[wq][r][lane];
      a.x += ax + bx; a.y += ay + by;
      acc2[wq][r][lane] = a;
    }
  }
  for (int r = 0; r < RPW; ++r) {
    int gr = gr0 + r;
    if (gr >= n) break;
    float2 a = acc2[wq][r][lane];
    float vx = a.x, vy = a.y;
    vx += __shfl_xor(vx, 32);          // cross-half sum
    vy += __shfl_xor(vy, 32);
    float m = fmaxf(vx, vy);
    for (int o = 16; o > 0; o >>= 1) m = fmaxf(m, __shfl_xor(m, o));
    float s = expf(vx - m) + expf(vy - m);
    for (int o = 16; o > 0; o >>= 1) s += __shfl_xor(s, o);
    float ls = logf(s);
    if (half == 0) {
      float2 o2 = { vx - m - ls, vy - m - ls };
      *(float2*)(out + (size_t)gr * 64 + 2 * c) = o2;
    }
  }
}

extern "C" void kernel_launch(void* const* d_in, const int* in_sizes, int n_in,
                              void* d_out, int out_size, void* d_ws, size_t ws_size,
                              hipStream_t stream) {
  const float* x  = (const float*)d_in[0];
  const int*   ei = (const int*)d_in[1];
  const float* W1 = (const float*)d_in[2];
  const float* b1 = (const float*)d_in[3];
  const float* W2 = (const float*)d_in[4];
  const float* b2 = (const float*)d_in[5];
  float* out = (float*)d_out;

  const int n = in_sizes[0] / N_FEAT;   // 50000
  const int E = in_sizes[1] / 2;        // 800000
  const int* src = ei;
  const int* dst = ei + E;
  const int m   = 4 * n;                // (dst, bucket) key space
  const int nb2 = (m + 255) / 256;      // 782 scan blocks (<=1024)
  const int nwv = (n + RPW - 1) / RPW;  // agg waves
  const int nbA = (nwv + 3) / 4;        // agg blocks

  auto align = [](size_t v) { return (v + 255) & ~(size_t)255; };
  char* ws = (char*)d_ws;
  size_t off = 0;
  int*      cnt2 = (int*)     (ws + off); off += align((size_t)m * 4);
  int*      rp2  = (int*)     (ws + off); off += align((size_t)(m + 1) * 4);
  float*    dinv = (float*)   (ws + off); off += align((size_t)n * 4);
  int*      rank = (int*)     (ws + off); off += align((size_t)E * 4);
  int*      bsum = (int*)     (ws + off); off += align(1024 * 4);
  int*      bbase= (int*)     (ws + off); off += align(1024 * 4);
  unsigned* desc = (unsigned*)(ws + off); off += align((size_t)(E + 3 * m + 64) * 4);
  unsigned* xwb  = (unsigned*)(ws + off); off += align((size_t)n * 64 * 4);  // bf16[n,128]
  unsigned* hb   = (unsigned*)(ws + off); off += align((size_t)n * 64 * 4);  // bf16[n,128]
  unsigned* hwb  = xwb;  // bf16[n,64] overlays xwb (dead after agg128)

  hipMemsetAsync(cnt2, 0, (size_t)m * 4, stream);
  k_hist<<<(E + 255) / 256, 256, 0, stream>>>(src, dst, cnt2, rank, E);
  k_bsum<<<nb2, 256, 0, stream>>>(cnt2, bsum, dinv, m, n);
  k_bscan<<<1, 1024, 0, stream>>>(bsum, bbase, nb2);
  k_scan2<<<nb2, 256, 0, stream>>>(cnt2, bbase, rp2, desc, m);
  k_fill<<<(E + 255) / 256, 256, 0, stream>>>(src, dst, rank, rp2, dinv, desc, E);

  // Layer 1
  k_gemm_mfma<128, true><<<(n + 63) / 64, 256, 0, stream>>>(
      x, W1, (unsigned short*)xwb, n);
  k_agg128L<<<nbA, 256, 0, stream>>>(desc, rp2, dinv, b1, xwb, hb, n);

  // Layer 2
  k_gemm_mfma<64, false><<<(n + 63) / 64, 256, 0, stream>>>(
      hb, W2, (unsigned short*)hwb, n);
  k_agg64L<<<nbA, 256, 0, stream>>>(desc, rp2, dinv, b2, hwb, out, n);
}